// Round 1
// baseline (436.805 us; speedup 1.0000x reference)
//
#include <hip/hip_runtime.h>
#include <math.h>

#define NNODES 65536
#define NEDGES 2097152
#define PGRAPH 1024
#define NGRAPH 64
#define CAP    36864   /* per-graph CSR capacity: E[count]=32768, sigma~180 -> 22 sigma margin */

/* ws layout (bytes) */
#define OFF_DEG   0u          /* int[65536]            */
#define OFF_FILL  262144u     /* int[65536]            */
#define OFF_POOL  524288u     /* float[64*32]          */
#define OFF_ROW   532480u     /* int[65536]            */
#define OFF_DIS   794624u     /* float[65536]          */
#define OFF_CSR   1056768u    /* ushort[64*CAP]        */
#define OFF_HS    5775360u    /* float[65536*32]       */
#define OFF_HBUF  14163968u   /* float[65536*32]       */
#define WS_TOTAL  22552576u

__global__ void k_deg(const int* __restrict__ dst, int* __restrict__ deg) {
    int e = blockIdx.x * 256 + threadIdx.x;
    atomicAdd(&deg[dst[e]], 1);
}

/* per-graph exclusive scan of deg -> row_start; also dis = rsqrt(deg+1) */
__global__ void k_scan(const int* __restrict__ deg, int* __restrict__ row_start,
                       float* __restrict__ dis) {
    int g = blockIdx.x;
    int t = threadIdx.x;
    int n = g * PGRAPH + t;
    int v = deg[n];
    int lane = t & 63;
    int wid  = t >> 6;
    int x = v;
    #pragma unroll
    for (int off = 1; off < 64; off <<= 1) {
        int y = __shfl_up(x, off, 64);
        if (lane >= off) x += y;
    }
    __shared__ int wsum[16];
    if (lane == 63) wsum[wid] = x;
    __syncthreads();
    if (t < 16) {
        int s = wsum[t];
        #pragma unroll
        for (int off = 1; off < 16; off <<= 1) {
            int y = __shfl_up(s, off, 16);
            if (t >= off) s += y;
        }
        wsum[t] = s;   /* inclusive over wave totals */
    }
    __syncthreads();
    int waveoff = (wid == 0) ? 0 : wsum[wid - 1];
    int excl = x + waveoff - v;
    row_start[n] = g * CAP + excl;
    dis[n] = rsqrtf((float)(v + 1));
}

__global__ void k_fill(const int* __restrict__ src, const int* __restrict__ dst,
                       const int* __restrict__ row_start, int* __restrict__ fill,
                       unsigned short* __restrict__ csr) {
    int e = blockIdx.x * 256 + threadIdx.x;
    int d = dst[e];
    int pos = row_start[d] + atomicAdd(&fill[d], 1);
    csr[pos] = (unsigned short)src[e];
}

/* hs[n] = dis[n] * (in[n] @ W^T), W is [32][DIN] row-major */
template <int DIN>
__global__ void k_hs(const float* __restrict__ in, const float* __restrict__ W,
                     const float* __restrict__ dis, float* __restrict__ out) {
    __shared__ float Ws[32 * DIN];
    int t = threadIdx.x;
    for (int i = t; i < 32 * DIN; i += 256) Ws[i] = W[i];
    __syncthreads();
    int n = blockIdx.x * 256 + t;
    float xr[DIN];
    const float4* in4 = (const float4*)(in + (size_t)n * DIN);
    #pragma unroll
    for (int k = 0; k < DIN / 4; k++) {
        float4 v = in4[k];
        xr[4*k] = v.x; xr[4*k+1] = v.y; xr[4*k+2] = v.z; xr[4*k+3] = v.w;
    }
    float dn = dis[n];
    float4* out4 = (float4*)(out + (size_t)n * 32);
    #pragma unroll
    for (int o4 = 0; o4 < 8; o4++) {
        float r[4];
        #pragma unroll
        for (int j = 0; j < 4; j++) {
            int o = o4 * 4 + j;
            float s = 0.f;
            #pragma unroll
            for (int i = 0; i < DIN; i++) s += xr[i] * Ws[o * DIN + i];
            r[j] = s * dn;
        }
        out4[o4] = make_float4(r[0], r[1], r[2], r[3]);
    }
}

/* out[n] = tanh(dis[n] * (sum_{e:dst=n} hs[src] + hs[n]) + b)   (8 lanes per node) */
__global__ void k_conv(const float* __restrict__ hs, const unsigned short* __restrict__ csr,
                       const int* __restrict__ row_start, const int* __restrict__ deg,
                       const float* __restrict__ dis, const float* __restrict__ bias,
                       float* __restrict__ out) {
    int id = blockIdx.x * 256 + threadIdx.x;
    int n = id >> 3;
    int q = id & 7;
    const float4* hs4 = (const float4*)hs;
    float4 acc = hs4[(size_t)n * 8 + q];   /* self-loop term */
    int start = row_start[n];
    int d = deg[n];
    for (int i = 0; i < d; i++) {
        int s = csr[start + i];
        float4 v = hs4[(size_t)s * 8 + q];
        acc.x += v.x; acc.y += v.y; acc.z += v.z; acc.w += v.w;
    }
    float dn = dis[n];
    float4 b = ((const float4*)bias)[q];
    float4 r;
    r.x = tanhf(dn * acc.x + b.x);
    r.y = tanhf(dn * acc.y + b.y);
    r.z = tanhf(dn * acc.z + b.z);
    r.w = tanhf(dn * acc.w + b.w);
    ((float4*)out)[(size_t)n * 8 + q] = r;
}

/* h3 = tanh(h @ Wl^T + bl); pooled[g] += sum over block's 256 nodes */
__global__ void k_pool(const float* __restrict__ h, const float* __restrict__ Wl,
                       const float* __restrict__ bl, float* __restrict__ pooled) {
    __shared__ float Ws[1024];
    __shared__ float partial[4][32];
    int t = threadIdx.x;
    for (int i = t; i < 1024; i += 256) Ws[i] = Wl[i];
    __syncthreads();
    int n = blockIdx.x * 256 + t;
    float hr[32];
    const float4* h4 = (const float4*)(h + (size_t)n * 32);
    #pragma unroll
    for (int k = 0; k < 8; k++) {
        float4 v = h4[k];
        hr[4*k] = v.x; hr[4*k+1] = v.y; hr[4*k+2] = v.z; hr[4*k+3] = v.w;
    }
    float h3[32];
    #pragma unroll
    for (int o = 0; o < 32; o++) {
        float s = bl[o];
        #pragma unroll
        for (int i = 0; i < 32; i++) s += hr[i] * Ws[o * 32 + i];
        h3[o] = tanhf(s);
    }
    /* butterfly reduce across 64 lanes */
    #pragma unroll
    for (int o = 0; o < 32; o++) {
        float v = h3[o];
        v += __shfl_xor(v, 1);  v += __shfl_xor(v, 2);  v += __shfl_xor(v, 4);
        v += __shfl_xor(v, 8);  v += __shfl_xor(v, 16); v += __shfl_xor(v, 32);
        h3[o] = v;
    }
    int lane = t & 63, wid = t >> 6;
    if (lane == 0) {
        #pragma unroll
        for (int o = 0; o < 32; o++) partial[wid][o] = h3[o];
    }
    __syncthreads();
    if (t < 32) {
        float s = partial[0][t] + partial[1][t] + partial[2][t] + partial[3][t];
        int g = blockIdx.x >> 2;
        atomicAdd(&pooled[g * 32 + t], s);
    }
}

/* whole MLP tail: 64 graphs x 32 lanes */
__global__ void k_final(const float* __restrict__ pooled, const float* __restrict__ share,
                        const float* __restrict__ Wp,  const float* __restrict__ bp,
                        const float* __restrict__ Vw1, const float* __restrict__ Vb1,
                        const float* __restrict__ Vw2, const float* __restrict__ Vb2,
                        const float* __restrict__ Vw3, const float* __restrict__ Vb3,
                        const float* __restrict__ Cw1, const float* __restrict__ Cb1,
                        const float* __restrict__ Cw2, const float* __restrict__ Cb2,
                        float* __restrict__ out) {
    int id = blockIdx.x * 256 + threadIdx.x;  /* 0..2047 */
    int b = id >> 5;
    int j = id & 31;
    float p = pooled[b * 32 + j];
    float h1v = bp[j];
    #pragma unroll
    for (int k = 0; k < 32; k++) h1v += Wp[j * 32 + k] * __shfl(p, k, 32);
    float s0 = share[b * 64 + j];
    float s1 = share[b * 64 + 32 + j];
    float t1 = Vb1[j];
    #pragma unroll
    for (int k = 0; k < 32; k++) {
        t1 += Vw1[j * 64 + k] * __shfl(s0, k, 32);
        t1 += Vw1[j * 64 + 32 + k] * __shfl(s1, k, 32);
    }
    t1 = tanhf(t1);
    float t2 = Vb2[j];
    #pragma unroll
    for (int k = 0; k < 32; k++) t2 += Vw2[j * 32 + k] * __shfl(t1, k, 32);
    t2 = tanhf(t2);
    float h2v = Vb3[j];
    #pragma unroll
    for (int k = 0; k < 32; k++) h2v += Vw3[j * 32 + k] * __shfl(t2, k, 32);
    float z = Cb1[j];
    #pragma unroll
    for (int k = 0; k < 32; k++) {
        z += Cw1[j * 64 + k] * __shfl(h1v, k, 32);
        z += Cw1[j * 64 + 32 + k] * __shfl(h2v, k, 32);
    }
    z = tanhf(z);
    float v = Cw2[j] * z;
    v += __shfl_down(v, 16, 32); v += __shfl_down(v, 8, 32);
    v += __shfl_down(v, 4, 32);  v += __shfl_down(v, 2, 32);
    v += __shfl_down(v, 1, 32);
    if (j == 0) out[b] = v + Cb2[0];
}

extern "C" void kernel_launch(void* const* d_in, const int* in_sizes, int n_in,
                              void* d_out, int out_size, void* d_ws, size_t ws_size,
                              hipStream_t stream) {
    const float* x     = (const float*)d_in[0];
    const int*   ei    = (const int*)d_in[1];     /* src = ei[0..E), dst = ei[E..2E) */
    const float* share = (const float*)d_in[3];
    const float* W1 = (const float*)d_in[4];  const float* b1 = (const float*)d_in[5];
    const float* W2 = (const float*)d_in[6];  const float* b2 = (const float*)d_in[7];
    const float* Wl = (const float*)d_in[8];  const float* bl = (const float*)d_in[9];
    const float* Wp = (const float*)d_in[10]; const float* bp = (const float*)d_in[11];
    const float* Vw1 = (const float*)d_in[12]; const float* Vb1 = (const float*)d_in[13];
    const float* Vw2 = (const float*)d_in[14]; const float* Vb2 = (const float*)d_in[15];
    const float* Vw3 = (const float*)d_in[16]; const float* Vb3 = (const float*)d_in[17];
    const float* Cw1 = (const float*)d_in[18]; const float* Cb1 = (const float*)d_in[19];
    const float* Cw2 = (const float*)d_in[20]; const float* Cb2 = (const float*)d_in[21];

    char* ws = (char*)d_ws;
    int*            deg       = (int*)(ws + OFF_DEG);
    int*            fill      = (int*)(ws + OFF_FILL);
    float*          pooled    = (float*)(ws + OFF_POOL);
    int*            row_start = (int*)(ws + OFF_ROW);
    float*          dis       = (float*)(ws + OFF_DIS);
    unsigned short* csr       = (unsigned short*)(ws + OFF_CSR);
    float*          hs        = (float*)(ws + OFF_HS);
    float*          hbuf      = (float*)(ws + OFF_HBUF);

    const int* srcp = ei;
    const int* dstp = ei + NEDGES;

    /* zero deg, fill, pooled */
    hipMemsetAsync(ws, 0, OFF_POOL + 64 * 32 * sizeof(float), stream);

    k_deg<<<NEDGES / 256, 256, 0, stream>>>(dstp, deg);
    k_scan<<<NGRAPH, PGRAPH, 0, stream>>>(deg, row_start, dis);
    k_fill<<<NEDGES / 256, 256, 0, stream>>>(srcp, dstp, row_start, fill, csr);

    k_hs<16><<<NNODES / 256, 256, 0, stream>>>(x, W1, dis, hs);
    k_conv<<<NNODES * 8 / 256, 256, 0, stream>>>(hs, csr, row_start, deg, dis, b1, hbuf);
    k_hs<32><<<NNODES / 256, 256, 0, stream>>>(hbuf, W2, dis, hs);
    k_conv<<<NNODES * 8 / 256, 256, 0, stream>>>(hs, csr, row_start, deg, dis, b2, hbuf);
    k_pool<<<NNODES / 256, 256, 0, stream>>>(hbuf, Wl, bl, pooled);
    k_final<<<8, 256, 0, stream>>>(pooled, share, Wp, bp, Vw1, Vb1, Vw2, Vb2,
                                   Vw3, Vb3, Cw1, Cb1, Cw2, Cb2, (float*)d_out);
}

// Round 2
// 265.358 us; speedup vs baseline: 1.6461x; 1.6461x over previous
//
#include <hip/hip_runtime.h>
#include <math.h>

#define NNODES 65536
#define NEDGES 2097152
#define PGRAPH 1024
#define NGRAPH 64
#define CAPE   34560   /* per-graph edge capacity: mean 32768, sigma~180 -> ~10 sigma margin */

/* ws layout (bytes) */
#define OFF_GFILL 0u          /* int[64]                           */
#define OFF_POOL  256u        /* float[64*32]                      */
#define OFF_ROW   8704u       /* int[65536]                        */
#define OFF_DEG   270848u     /* int[65536]                        */
#define OFF_DIS   532992u     /* float[65536]                      */
#define OFF_CSR   795136u     /* ushort[64*CAPE]  = 4423680 B      */
#define OFF_EBUF  5218816u    /* uint[64*CAPE] = 8847360 B; hs aliases this after k_csr */
#define OFF_HBUF  14066176u   /* float[65536*32] = 8388608 B       */
/* total 22454784 B */

/* ---- bucket edges by graph id (block-local counting sort, contiguous writes) ---- */
__global__ void k_bucket(const int* __restrict__ src, const int* __restrict__ dst,
                         int* __restrict__ gfill, unsigned int* __restrict__ ebuf) {
    __shared__ unsigned int sorted[8192];
    __shared__ int hist[64], lexcl[64], gbase[64], lfill[64];
    int t = threadIdx.x;
    if (t < 64) { hist[t] = 0; lfill[t] = 0; }
    __syncthreads();

    int base = blockIdx.x * 8192;
    unsigned int pk[32];
    int gg[32];
    #pragma unroll
    for (int k = 0; k < 32; k++) {
        int e = base + k * 256 + t;
        int s = src[e], d = dst[e];
        int g = s >> 10;
        pk[k] = (unsigned int)((s & 1023) | ((d & 1023) << 10) | (g << 20));
        gg[k] = g;
        atomicAdd(&hist[g], 1);
    }
    __syncthreads();
    if (t < 64) {
        int h = hist[t];
        int x = h;
        #pragma unroll
        for (int off = 1; off < 64; off <<= 1) {
            int y = __shfl_up(x, off, 64);
            if (t >= off) x += y;
        }
        lexcl[t] = x - h;
        gbase[t] = atomicAdd(&gfill[t], h);
    }
    __syncthreads();
    #pragma unroll
    for (int k = 0; k < 32; k++) {
        int g = gg[k];
        int pos = lexcl[g] + atomicAdd(&lfill[g], 1);
        sorted[pos] = pk[k];
    }
    __syncthreads();
    for (int i = t; i < 8192; i += 256) {
        unsigned int p = sorted[i];
        int g = p >> 20;
        int idx = gbase[g] + (i - lexcl[g]);
        ebuf[(size_t)g * CAPE + idx] = p;
    }
}

/* ---- per-graph: degree, dis, row_start, CSR (all in LDS, coalesced global writes) ---- */
__global__ void k_csr(const unsigned int* __restrict__ ebuf, const int* __restrict__ gfill,
                      int* __restrict__ deg, float* __restrict__ dis,
                      int* __restrict__ row_start, unsigned short* __restrict__ csr) {
    __shared__ int ldeg[1024], lrow[1024], lfill[1024];
    __shared__ unsigned short lcsr[CAPE];
    __shared__ int wsum[16];
    int g = blockIdx.x;
    int t = threadIdx.x;
    int cnt = gfill[g];
    const unsigned int* eb = ebuf + (size_t)g * CAPE;

    ldeg[t] = 0;
    __syncthreads();
    for (int i = t; i < cnt; i += 1024) {
        unsigned int v = eb[i];
        atomicAdd(&ldeg[(v >> 10) & 1023], 1);
    }
    __syncthreads();

    int dv = ldeg[t];
    int lane = t & 63, wid = t >> 6;
    int x = dv;
    #pragma unroll
    for (int off = 1; off < 64; off <<= 1) {
        int y = __shfl_up(x, off, 64);
        if (lane >= off) x += y;
    }
    if (lane == 63) wsum[wid] = x;
    __syncthreads();
    if (t < 16) {
        int s = wsum[t];
        #pragma unroll
        for (int off = 1; off < 16; off <<= 1) {
            int y = __shfl_up(s, off, 16);
            if (t >= off) s += y;
        }
        wsum[t] = s;
    }
    __syncthreads();
    int excl = x + ((wid == 0) ? 0 : wsum[wid - 1]) - dv;

    int n = g * PGRAPH + t;
    deg[n] = dv;
    dis[n] = rsqrtf((float)(dv + 1));
    row_start[n] = g * CAPE + excl;
    lrow[t] = excl;
    lfill[t] = 0;
    __syncthreads();

    for (int i = t; i < cnt; i += 1024) {
        unsigned int v = eb[i];
        int s = v & 1023;
        int d = (v >> 10) & 1023;
        int pos = lrow[d] + atomicAdd(&lfill[d], 1);
        lcsr[pos] = (unsigned short)s;
    }
    __syncthreads();
    for (int i = t; i < cnt; i += 1024) csr[(size_t)g * CAPE + i] = lcsr[i];
}

/* hs[n] = dis[n] * (in[n] @ W^T), W is [32][DIN] row-major */
template <int DIN>
__global__ void k_hs(const float* __restrict__ in, const float* __restrict__ W,
                     const float* __restrict__ dis, float* __restrict__ out) {
    __shared__ float Ws[32 * DIN];
    int t = threadIdx.x;
    for (int i = t; i < 32 * DIN; i += 256) Ws[i] = W[i];
    __syncthreads();
    int n = blockIdx.x * 256 + t;
    float xr[DIN];
    const float4* in4 = (const float4*)(in + (size_t)n * DIN);
    #pragma unroll
    for (int k = 0; k < DIN / 4; k++) {
        float4 v = in4[k];
        xr[4*k] = v.x; xr[4*k+1] = v.y; xr[4*k+2] = v.z; xr[4*k+3] = v.w;
    }
    float dn = dis[n];
    float4* out4 = (float4*)(out + (size_t)n * 32);
    #pragma unroll
    for (int o4 = 0; o4 < 8; o4++) {
        float r[4];
        #pragma unroll
        for (int j = 0; j < 4; j++) {
            int o = o4 * 4 + j;
            float s = 0.f;
            #pragma unroll
            for (int i = 0; i < DIN; i++) s += xr[i] * Ws[o * DIN + i];
            r[j] = s * dn;
        }
        out4[o4] = make_float4(r[0], r[1], r[2], r[3]);
    }
}

/* out[n] = tanh(dis[n] * (sum_{e:dst=n} hs[src] + hs[n]) + b)   (8 lanes per node) */
__global__ void k_conv(const float* __restrict__ hs, const unsigned short* __restrict__ csr,
                       const int* __restrict__ row_start, const int* __restrict__ deg,
                       const float* __restrict__ dis, const float* __restrict__ bias,
                       float* __restrict__ out) {
    int id = blockIdx.x * 256 + threadIdx.x;
    int n = id >> 3;
    int q = id & 7;
    int g = n >> 10;
    const float4* hs4 = (const float4*)hs;
    size_t gb = (size_t)g * PGRAPH * 8;
    float4 acc = hs4[(size_t)n * 8 + q];   /* self-loop term */
    int start = row_start[n];
    int d = deg[n];
    for (int i = 0; i < d; i++) {
        int s = csr[start + i];
        float4 v = hs4[gb + (size_t)s * 8 + q];
        acc.x += v.x; acc.y += v.y; acc.z += v.z; acc.w += v.w;
    }
    float dn = dis[n];
    float4 b = ((const float4*)bias)[q];
    float4 r;
    r.x = tanhf(dn * acc.x + b.x);
    r.y = tanhf(dn * acc.y + b.y);
    r.z = tanhf(dn * acc.z + b.z);
    r.w = tanhf(dn * acc.w + b.w);
    ((float4*)out)[(size_t)n * 8 + q] = r;
}

/* h3 = tanh(h @ Wl^T + bl); pooled[g] += sum over block's 256 nodes */
__global__ void k_pool(const float* __restrict__ h, const float* __restrict__ Wl,
                       const float* __restrict__ bl, float* __restrict__ pooled) {
    __shared__ float Ws[1024];
    __shared__ float partial[4][32];
    int t = threadIdx.x;
    for (int i = t; i < 1024; i += 256) Ws[i] = Wl[i];
    __syncthreads();
    int n = blockIdx.x * 256 + t;
    float hr[32];
    const float4* h4 = (const float4*)(h + (size_t)n * 32);
    #pragma unroll
    for (int k = 0; k < 8; k++) {
        float4 v = h4[k];
        hr[4*k] = v.x; hr[4*k+1] = v.y; hr[4*k+2] = v.z; hr[4*k+3] = v.w;
    }
    float h3[32];
    #pragma unroll
    for (int o = 0; o < 32; o++) {
        float s = bl[o];
        #pragma unroll
        for (int i = 0; i < 32; i++) s += hr[i] * Ws[o * 32 + i];
        h3[o] = tanhf(s);
    }
    #pragma unroll
    for (int o = 0; o < 32; o++) {
        float v = h3[o];
        v += __shfl_xor(v, 1);  v += __shfl_xor(v, 2);  v += __shfl_xor(v, 4);
        v += __shfl_xor(v, 8);  v += __shfl_xor(v, 16); v += __shfl_xor(v, 32);
        h3[o] = v;
    }
    int lane = t & 63, wid = t >> 6;
    if (lane == 0) {
        #pragma unroll
        for (int o = 0; o < 32; o++) partial[wid][o] = h3[o];
    }
    __syncthreads();
    if (t < 32) {
        float s = partial[0][t] + partial[1][t] + partial[2][t] + partial[3][t];
        int g = blockIdx.x >> 2;
        atomicAdd(&pooled[g * 32 + t], s);
    }
}

/* whole MLP tail: 64 graphs x 32 lanes */
__global__ void k_final(const float* __restrict__ pooled, const float* __restrict__ share,
                        const float* __restrict__ Wp,  const float* __restrict__ bp,
                        const float* __restrict__ Vw1, const float* __restrict__ Vb1,
                        const float* __restrict__ Vw2, const float* __restrict__ Vb2,
                        const float* __restrict__ Vw3, const float* __restrict__ Vb3,
                        const float* __restrict__ Cw1, const float* __restrict__ Cb1,
                        const float* __restrict__ Cw2, const float* __restrict__ Cb2,
                        float* __restrict__ out) {
    int id = blockIdx.x * 256 + threadIdx.x;  /* 0..2047 */
    int b = id >> 5;
    int j = id & 31;
    float p = pooled[b * 32 + j];
    float h1v = bp[j];
    #pragma unroll
    for (int k = 0; k < 32; k++) h1v += Wp[j * 32 + k] * __shfl(p, k, 32);
    float s0 = share[b * 64 + j];
    float s1 = share[b * 64 + 32 + j];
    float t1 = Vb1[j];
    #pragma unroll
    for (int k = 0; k < 32; k++) {
        t1 += Vw1[j * 64 + k] * __shfl(s0, k, 32);
        t1 += Vw1[j * 64 + 32 + k] * __shfl(s1, k, 32);
    }
    t1 = tanhf(t1);
    float t2 = Vb2[j];
    #pragma unroll
    for (int k = 0; k < 32; k++) t2 += Vw2[j * 32 + k] * __shfl(t1, k, 32);
    t2 = tanhf(t2);
    float h2v = Vb3[j];
    #pragma unroll
    for (int k = 0; k < 32; k++) h2v += Vw3[j * 32 + k] * __shfl(t2, k, 32);
    float z = Cb1[j];
    #pragma unroll
    for (int k = 0; k < 32; k++) {
        z += Cw1[j * 64 + k] * __shfl(h1v, k, 32);
        z += Cw1[j * 64 + 32 + k] * __shfl(h2v, k, 32);
    }
    z = tanhf(z);
    float v = Cw2[j] * z;
    v += __shfl_down(v, 16, 32); v += __shfl_down(v, 8, 32);
    v += __shfl_down(v, 4, 32);  v += __shfl_down(v, 2, 32);
    v += __shfl_down(v, 1, 32);
    if (j == 0) out[b] = v + Cb2[0];
}

extern "C" void kernel_launch(void* const* d_in, const int* in_sizes, int n_in,
                              void* d_out, int out_size, void* d_ws, size_t ws_size,
                              hipStream_t stream) {
    const float* x     = (const float*)d_in[0];
    const int*   ei    = (const int*)d_in[1];     /* src = ei[0..E), dst = ei[E..2E) */
    const float* share = (const float*)d_in[3];
    const float* W1 = (const float*)d_in[4];  const float* b1 = (const float*)d_in[5];
    const float* W2 = (const float*)d_in[6];  const float* b2 = (const float*)d_in[7];
    const float* Wl = (const float*)d_in[8];  const float* bl = (const float*)d_in[9];
    const float* Wp = (const float*)d_in[10]; const float* bp = (const float*)d_in[11];
    const float* Vw1 = (const float*)d_in[12]; const float* Vb1 = (const float*)d_in[13];
    const float* Vw2 = (const float*)d_in[14]; const float* Vb2 = (const float*)d_in[15];
    const float* Vw3 = (const float*)d_in[16]; const float* Vb3 = (const float*)d_in[17];
    const float* Cw1 = (const float*)d_in[18]; const float* Cb1 = (const float*)d_in[19];
    const float* Cw2 = (const float*)d_in[20]; const float* Cb2 = (const float*)d_in[21];

    char* ws = (char*)d_ws;
    int*            gfill     = (int*)(ws + OFF_GFILL);
    float*          pooled    = (float*)(ws + OFF_POOL);
    int*            row_start = (int*)(ws + OFF_ROW);
    int*            deg       = (int*)(ws + OFF_DEG);
    float*          dis       = (float*)(ws + OFF_DIS);
    unsigned short* csr       = (unsigned short*)(ws + OFF_CSR);
    unsigned int*   ebuf      = (unsigned int*)(ws + OFF_EBUF);
    float*          hs        = (float*)(ws + OFF_EBUF);   /* aliases ebuf (dead after k_csr) */
    float*          hbuf      = (float*)(ws + OFF_HBUF);

    const int* srcp = ei;
    const int* dstp = ei + NEDGES;

    /* zero gfill + pooled */
    hipMemsetAsync(ws, 0, 8448, stream);

    k_bucket<<<256, 256, 0, stream>>>(srcp, dstp, gfill, ebuf);
    k_csr<<<NGRAPH, 1024, 0, stream>>>(ebuf, gfill, deg, dis, row_start, csr);

    k_hs<16><<<NNODES / 256, 256, 0, stream>>>(x, W1, dis, hs);
    k_conv<<<NNODES * 8 / 256, 256, 0, stream>>>(hs, csr, row_start, deg, dis, b1, hbuf);
    k_hs<32><<<NNODES / 256, 256, 0, stream>>>(hbuf, W2, dis, hs);
    k_conv<<<NNODES * 8 / 256, 256, 0, stream>>>(hs, csr, row_start, deg, dis, b2, hbuf);
    k_pool<<<NNODES / 256, 256, 0, stream>>>(hbuf, Wl, bl, pooled);
    k_final<<<8, 256, 0, stream>>>(pooled, share, Wp, bp, Vw1, Vb1, Vw2, Vb2,
                                   Vw3, Vb3, Cw1, Cb1, Cw2, Cb2, (float*)d_out);
}

// Round 3
// 200.162 us; speedup vs baseline: 2.1823x; 1.3257x over previous
//
#include <hip/hip_runtime.h>
#include <math.h>

#define NNODES 65536
#define NEDGES 2097152
#define PGRAPH 1024
#define NGRAPH 64
#define CAPE   34560   /* per-graph edge capacity: mean 32768, sigma~180 -> ~10 sigma margin */

/* ws layout (bytes) */
#define OFF_GFILL 0u          /* int[64]                           */
#define OFF_POOL  256u        /* float[64*32]                      */
#define OFF_ROW   8704u       /* int[65536]                        */
#define OFF_DEG   270848u     /* int[65536]                        */
#define OFF_DIS   532992u     /* float[65536]                      */
#define OFF_CSR   795136u     /* ushort[64*CAPE]  = 4423680 B      */
#define OFF_EBUF  5218816u    /* uint[64*CAPE] = 8847360 B         */
#define OFF_HBUF  14066176u   /* float[65536*32] = 8388608 B (h1)  */

/* ---- bucket edges by graph id (block-local counting sort, contiguous writes) ---- */
__global__ void k_bucket(const int* __restrict__ src, const int* __restrict__ dst,
                         int* __restrict__ gfill, unsigned int* __restrict__ ebuf) {
    __shared__ unsigned int sorted[8192];
    __shared__ int hist[64], lexcl[64], gbase[64], lfill[64];
    int t = threadIdx.x;
    if (t < 64) { hist[t] = 0; lfill[t] = 0; }
    __syncthreads();

    int base = blockIdx.x * 8192;
    unsigned int pk[32];
    int gg[32];
    #pragma unroll
    for (int k = 0; k < 32; k++) {
        int e = base + k * 256 + t;
        int s = src[e], d = dst[e];
        int g = s >> 10;
        pk[k] = (unsigned int)((s & 1023) | ((d & 1023) << 10) | (g << 20));
        gg[k] = g;
        atomicAdd(&hist[g], 1);
    }
    __syncthreads();
    if (t < 64) {
        int h = hist[t];
        int x = h;
        #pragma unroll
        for (int off = 1; off < 64; off <<= 1) {
            int y = __shfl_up(x, off, 64);
            if (t >= off) x += y;
        }
        lexcl[t] = x - h;
        gbase[t] = atomicAdd(&gfill[t], h);
    }
    __syncthreads();
    #pragma unroll
    for (int k = 0; k < 32; k++) {
        int g = gg[k];
        int pos = lexcl[g] + atomicAdd(&lfill[g], 1);
        sorted[pos] = pk[k];
    }
    __syncthreads();
    for (int i = t; i < 8192; i += 256) {
        unsigned int p = sorted[i];
        int g = p >> 20;
        int idx = gbase[g] + (i - lexcl[g]);
        ebuf[(size_t)g * CAPE + idx] = p;
    }
}

/* ---- per-graph: degree, dis, row_start, CSR (all in LDS, coalesced global writes) ---- */
__global__ void k_csr(const unsigned int* __restrict__ ebuf, const int* __restrict__ gfill,
                      int* __restrict__ deg, float* __restrict__ dis,
                      int* __restrict__ row_start, unsigned short* __restrict__ csr) {
    __shared__ int ldeg[1024], lrow[1024], lfill[1024];
    __shared__ unsigned short lcsr[CAPE];
    __shared__ int wsum[16];
    int g = blockIdx.x;
    int t = threadIdx.x;
    int cnt = gfill[g];
    const unsigned int* eb = ebuf + (size_t)g * CAPE;

    ldeg[t] = 0;
    __syncthreads();
    for (int i = t; i < cnt; i += 1024) {
        unsigned int v = eb[i];
        atomicAdd(&ldeg[(v >> 10) & 1023], 1);
    }
    __syncthreads();

    int dv = ldeg[t];
    int lane = t & 63, wid = t >> 6;
    int x = dv;
    #pragma unroll
    for (int off = 1; off < 64; off <<= 1) {
        int y = __shfl_up(x, off, 64);
        if (lane >= off) x += y;
    }
    if (lane == 63) wsum[wid] = x;
    __syncthreads();
    if (t < 16) {
        int s = wsum[t];
        #pragma unroll
        for (int off = 1; off < 16; off <<= 1) {
            int y = __shfl_up(s, off, 16);
            if (t >= off) s += y;
        }
        wsum[t] = s;
    }
    __syncthreads();
    int excl = x + ((wid == 0) ? 0 : wsum[wid - 1]) - dv;

    int n = g * PGRAPH + t;
    deg[n] = dv;
    dis[n] = rsqrtf((float)(dv + 1));
    row_start[n] = g * CAPE + excl;
    lrow[t] = excl;
    lfill[t] = 0;
    __syncthreads();

    for (int i = t; i < cnt; i += 1024) {
        unsigned int v = eb[i];
        int s = v & 1023;
        int d = (v >> 10) & 1023;
        int pos = lrow[d] + atomicAdd(&lfill[d], 1);
        lcsr[pos] = (unsigned short)s;
    }
    __syncthreads();
    for (int i = t; i < cnt; i += 1024) csr[(size_t)g * CAPE + i] = lcsr[i];
}

/* ---- fused GCN layer: stage hs=dis*(in@W^T) for the whole graph into LDS
   (XOR-swizzled, bank-conflict-free), gather from LDS, tanh.
   FINAL variant also fuses h3 = tanh(h2@Wl^T+bl) and block pooling. ---- */
template <int DIN, bool FINAL>
__global__ __launch_bounds__(1024, 1) void k_conv(
        const float* __restrict__ in, const float* __restrict__ W,
        const float* __restrict__ bias, const float* __restrict__ dis,
        const int* __restrict__ row_start, const int* __restrict__ deg,
        const unsigned short* __restrict__ csr,
        const float* __restrict__ Wl, const float* __restrict__ bl,
        float* __restrict__ out) {
    __shared__ float hsL[PGRAPH * 32];     /* 128 KB, float4-swizzled rows */
    __shared__ float WlL[32 * 33];         /* padded stride 33 */
    float4* hsL4 = (float4*)hsL;

    int t = threadIdx.x;
    int g = blockIdx.x >> 2;
    int part = blockIdx.x & 3;

    if (FINAL) { WlL[(t >> 5) * 33 + (t & 31)] = Wl[t]; }

    /* phase 1: hs for ALL 1024 nodes of this graph */
    {
        int n = (g << 10) + t;
        float inr[DIN];
        const float4* in4 = (const float4*)(in + (size_t)n * DIN);
        #pragma unroll
        for (int k = 0; k < DIN / 4; k++) {
            float4 v = in4[k];
            inr[4*k] = v.x; inr[4*k+1] = v.y; inr[4*k+2] = v.z; inr[4*k+3] = v.w;
        }
        float dn = dis[n];
        int sw = t & 7;
        #pragma unroll
        for (int o4 = 0; o4 < 8; o4++) {
            float r[4];
            #pragma unroll
            for (int j = 0; j < 4; j++) {
                int o = o4 * 4 + j;
                float s = 0.f;
                #pragma unroll
                for (int k = 0; k < DIN; k++) s += inr[k] * W[o * DIN + k];
                r[j] = s * dn;
            }
            hsL4[t * 8 + (o4 ^ sw)] = make_float4(r[0], r[1], r[2], r[3]);
        }
    }
    __syncthreads();

    /* phase 2: gather for this block's 256 nodes (8 lanes/node, 2 passes) */
    int q = t & 7;
    int grp = t >> 3;
    float4 racc[2];
    #pragma unroll
    for (int pass = 0; pass < 2; pass++) {
        int ln = part * 256 + pass * 128 + grp;      /* local node 0..1023 */
        int nn = (g << 10) + ln;
        float dnd = dis[nn];
        int st = row_start[nn];
        int d  = deg[nn];
        float4 acc = hsL4[ln * 8 + (q ^ (ln & 7))];  /* self-loop */
        for (int i = 0; i < d; i++) {
            int s = csr[st + i];
            float4 v = hsL4[s * 8 + (q ^ (s & 7))];
            acc.x += v.x; acc.y += v.y; acc.z += v.z; acc.w += v.w;
        }
        float4 bb = ((const float4*)bias)[q];
        float4 r;
        r.x = tanhf(dnd * acc.x + bb.x);
        r.y = tanhf(dnd * acc.y + bb.y);
        r.z = tanhf(dnd * acc.z + bb.z);
        r.w = tanhf(dnd * acc.w + bb.w);
        if (!FINAL) ((float4*)out)[(size_t)nn * 8 + q] = r;
        else        racc[pass] = r;
    }

    if (FINAL) {
        /* phase 3: h3 = tanh(h2@Wl^T + bl), pool over this block's 256 nodes */
        __syncthreads();
        #pragma unroll
        for (int pass = 0; pass < 2; pass++) {
            int lnn = pass * 128 + grp;              /* 0..255 */
            hsL4[lnn * 8 + (q ^ (lnn & 7))] = racc[pass];
        }
        __syncthreads();
        int o = t & 31, seg = t >> 5;
        float ps = 0.f;
        #pragma unroll
        for (int j = 0; j < 8; j++) {
            int nl = seg * 8 + j;
            int swn = nl & 7;
            float s = bl[o];
            #pragma unroll
            for (int k = 0; k < 32; k++) {
                float h2v = hsL[nl * 32 + ((((k >> 2) ^ swn) << 2) | (k & 3))];
                s += h2v * WlL[o * 33 + k];
            }
            ps += tanhf(s);
        }
        float* psum = hsL + 8192;                    /* rows 0..255 hold h2; this is free */
        psum[t] = ps;
        __syncthreads();
        if (t < 32) {
            float tot = 0.f;
            for (int s = 0; s < 32; s++) tot += psum[s * 32 + t];
            atomicAdd(&out[g * 32 + t], tot);
        }
    }
}

/* whole MLP tail: 64 graphs x 32 lanes */
__global__ void k_final(const float* __restrict__ pooled, const float* __restrict__ share,
                        const float* __restrict__ Wp,  const float* __restrict__ bp,
                        const float* __restrict__ Vw1, const float* __restrict__ Vb1,
                        const float* __restrict__ Vw2, const float* __restrict__ Vb2,
                        const float* __restrict__ Vw3, const float* __restrict__ Vb3,
                        const float* __restrict__ Cw1, const float* __restrict__ Cb1,
                        const float* __restrict__ Cw2, const float* __restrict__ Cb2,
                        float* __restrict__ out) {
    int id = blockIdx.x * 256 + threadIdx.x;  /* 0..2047 */
    int b = id >> 5;
    int j = id & 31;
    float p = pooled[b * 32 + j];
    float h1v = bp[j];
    #pragma unroll
    for (int k = 0; k < 32; k++) h1v += Wp[j * 32 + k] * __shfl(p, k, 32);
    float s0 = share[b * 64 + j];
    float s1 = share[b * 64 + 32 + j];
    float t1 = Vb1[j];
    #pragma unroll
    for (int k = 0; k < 32; k++) {
        t1 += Vw1[j * 64 + k] * __shfl(s0, k, 32);
        t1 += Vw1[j * 64 + 32 + k] * __shfl(s1, k, 32);
    }
    t1 = tanhf(t1);
    float t2 = Vb2[j];
    #pragma unroll
    for (int k = 0; k < 32; k++) t2 += Vw2[j * 32 + k] * __shfl(t1, k, 32);
    t2 = tanhf(t2);
    float h2v = Vb3[j];
    #pragma unroll
    for (int k = 0; k < 32; k++) h2v += Vw3[j * 32 + k] * __shfl(t2, k, 32);
    float z = Cb1[j];
    #pragma unroll
    for (int k = 0; k < 32; k++) {
        z += Cw1[j * 64 + k] * __shfl(h1v, k, 32);
        z += Cw1[j * 64 + 32 + k] * __shfl(h2v, k, 32);
    }
    z = tanhf(z);
    float v = Cw2[j] * z;
    v += __shfl_down(v, 16, 32); v += __shfl_down(v, 8, 32);
    v += __shfl_down(v, 4, 32);  v += __shfl_down(v, 2, 32);
    v += __shfl_down(v, 1, 32);
    if (j == 0) out[b] = v + Cb2[0];
}

extern "C" void kernel_launch(void* const* d_in, const int* in_sizes, int n_in,
                              void* d_out, int out_size, void* d_ws, size_t ws_size,
                              hipStream_t stream) {
    const float* x     = (const float*)d_in[0];
    const int*   ei    = (const int*)d_in[1];     /* src = ei[0..E), dst = ei[E..2E) */
    const float* share = (const float*)d_in[3];
    const float* W1 = (const float*)d_in[4];  const float* b1 = (const float*)d_in[5];
    const float* W2 = (const float*)d_in[6];  const float* b2 = (const float*)d_in[7];
    const float* Wl = (const float*)d_in[8];  const float* bl = (const float*)d_in[9];
    const float* Wp = (const float*)d_in[10]; const float* bp = (const float*)d_in[11];
    const float* Vw1 = (const float*)d_in[12]; const float* Vb1 = (const float*)d_in[13];
    const float* Vw2 = (const float*)d_in[14]; const float* Vb2 = (const float*)d_in[15];
    const float* Vw3 = (const float*)d_in[16]; const float* Vb3 = (const float*)d_in[17];
    const float* Cw1 = (const float*)d_in[18]; const float* Cb1 = (const float*)d_in[19];
    const float* Cw2 = (const float*)d_in[20]; const float* Cb2 = (const float*)d_in[21];

    char* ws = (char*)d_ws;
    int*            gfill     = (int*)(ws + OFF_GFILL);
    float*          pooled    = (float*)(ws + OFF_POOL);
    int*            row_start = (int*)(ws + OFF_ROW);
    int*            deg       = (int*)(ws + OFF_DEG);
    float*          dis       = (float*)(ws + OFF_DIS);
    unsigned short* csr       = (unsigned short*)(ws + OFF_CSR);
    unsigned int*   ebuf      = (unsigned int*)(ws + OFF_EBUF);
    float*          h1        = (float*)(ws + OFF_HBUF);

    const int* srcp = ei;
    const int* dstp = ei + NEDGES;

    /* zero gfill + pooled */
    hipMemsetAsync(ws, 0, 8448, stream);

    k_bucket<<<256, 256, 0, stream>>>(srcp, dstp, gfill, ebuf);
    k_csr<<<NGRAPH, 1024, 0, stream>>>(ebuf, gfill, deg, dis, row_start, csr);

    k_conv<16, false><<<256, 1024, 0, stream>>>(x,  W1, b1, dis, row_start, deg, csr,
                                                Wl, bl, h1);
    k_conv<32, true ><<<256, 1024, 0, stream>>>(h1, W2, b2, dis, row_start, deg, csr,
                                                Wl, bl, pooled);
    k_final<<<8, 256, 0, stream>>>(pooled, share, Wp, bp, Vw1, Vb1, Vw2, Vb2,
                                   Vw3, Vb3, Cw1, Cb1, Cw2, Cb2, (float*)d_out);
}

// Round 4
// 191.494 us; speedup vs baseline: 2.2810x; 1.0453x over previous
//
#include <hip/hip_runtime.h>
#include <math.h>

#define NNODES 65536
#define NEDGES 2097152
#define PGRAPH 1024
#define NGRAPH 64
#define CAPE_E 34560   /* per-graph edge cap: mean 32768, sigma~180 -> +10 sigma  */
#define CAPQ   9728    /* per-quarter CSR cap: mean 8192 + align-pad<=768 + 8.5σ */
#define CSRG   (4 * CAPQ)

/* ws layout (bytes) */
#define OFF_GFILL 0u          /* int[64]                            */
#define OFF_POOL4 256u        /* float[256*32] partial pools        */
#define OFF_ROWI  33024u      /* uint[65536]  (start<<16)|deg       */
#define OFF_DIS   295168u     /* float[65536]                       */
#define OFF_CSR   557312u     /* ushort[64*CSRG] = 4980736 B        */
#define OFF_EBUF  5538048u    /* uint[64*CAPE_E] = 8847360 B        */
#define OFF_H1    14385408u   /* float[65536*32] = 8388608 B        */

__device__ __forceinline__ float ftanh(float x) {
    float e = __expf(2.f * x);
    return 1.f - 2.f * __builtin_amdgcn_rcpf(e + 1.f);
}

/* ---- bucket edges by graph id (block-local counting sort, contiguous writes) ---- */
__global__ void k_bucket(const int* __restrict__ src, const int* __restrict__ dst,
                         int* __restrict__ gfill, unsigned int* __restrict__ ebuf) {
    __shared__ unsigned int sorted[8192];
    __shared__ int hist[64], lexcl[64], gbase[64], lfill[64];
    int t = threadIdx.x;
    if (t < 64) { hist[t] = 0; lfill[t] = 0; }
    __syncthreads();

    const int4* src4 = (const int4*)(src + blockIdx.x * 8192);
    const int4* dst4 = (const int4*)(dst + blockIdx.x * 8192);
    unsigned int pk[32];
    #pragma unroll
    for (int k = 0; k < 8; k++) {
        int4 s4 = src4[k * 256 + t];
        int4 d4 = dst4[k * 256 + t];
        int ss[4] = { s4.x, s4.y, s4.z, s4.w };
        int dd[4] = { d4.x, d4.y, d4.z, d4.w };
        #pragma unroll
        for (int j = 0; j < 4; j++) {
            int g = ss[j] >> 10;
            pk[k * 4 + j] = (unsigned int)((ss[j] & 1023) | ((dd[j] & 1023) << 10) | (g << 20));
            atomicAdd(&hist[g], 1);
        }
    }
    __syncthreads();
    if (t < 64) {
        int h = hist[t];
        int x = h;
        #pragma unroll
        for (int off = 1; off < 64; off <<= 1) {
            int y = __shfl_up(x, off, 64);
            if (t >= off) x += y;
        }
        lexcl[t] = x - h;
        gbase[t] = atomicAdd(&gfill[t], h);
    }
    __syncthreads();
    #pragma unroll
    for (int k = 0; k < 32; k++) {
        int g = pk[k] >> 20;
        int pos = lexcl[g] + atomicAdd(&lfill[g], 1);
        sorted[pos] = pk[k];
    }
    __syncthreads();
    for (int i = t; i < 8192; i += 256) {
        unsigned int p = sorted[i];
        int g = p >> 20;
        ebuf[(size_t)g * CAPE_E + gbase[g] + (i - lexcl[g])] = p;
    }
}

/* ---- fused: per-quarter CSR build (LDS) + GCN layer 1 (LDS-resident gather) ----
   block = (g, part): histogram all graph edges -> deg/dis local; build 4-aligned
   CSR for its 256 dst nodes with zero-row(1024) padding; stage hs for all 1024
   nodes; gather from LDS; write h1 + csr/rowinfo/dis for conv2. */
__global__ __launch_bounds__(1024, 1) void k_build_conv1(
        const float* __restrict__ x, const float* __restrict__ W,
        const float* __restrict__ bias,
        const unsigned int* __restrict__ ebuf, const int* __restrict__ gfill,
        float* __restrict__ disg, unsigned int* __restrict__ rowinfo,
        unsigned short* __restrict__ csr, float* __restrict__ h1) {
    __shared__ float hsL[1025 * 32];          /* 131200 B, row 1024 = zeros */
    __shared__ unsigned short lcsr[CAPQ];     /* 19456 B */
    __shared__ int uhist[1024];
    __shared__ int lrow[256], lfill[256];
    __shared__ int wsum[4];
    float4* hsL4 = (float4*)hsL;

    int t = threadIdx.x;
    int g = blockIdx.x >> 2, part = blockIdx.x & 3;
    int cnt = gfill[g];
    const unsigned int* eb = ebuf + (size_t)g * CAPE_E;

    uhist[t] = 0;
    if (t < 32) hsL[1024 * 32 + t] = 0.f;     /* zero row */
    __syncthreads();
    for (int i = t; i < cnt; i += 1024) atomicAdd(&uhist[(eb[i] >> 10) & 1023], 1);
    __syncthreads();

    int dv_own = uhist[t];
    float dis_own = rsqrtf((float)(dv_own + 1));

    /* 256-wide exclusive scan of 4-aligned quarter degrees */
    int dq = 0, r4 = 0;
    if (t < 256) { dq = uhist[part * 256 + t]; r4 = (dq + 3) & ~3; }
    int lane = t & 63, wid = t >> 6;
    int xx = r4;
    #pragma unroll
    for (int off = 1; off < 64; off <<= 1) {
        int y = __shfl_up(xx, off, 64);
        if (lane >= off) xx += y;
    }
    if (t < 256 && lane == 63) wsum[wid] = xx;
    __syncthreads();
    if (t < 256) {
        int pre = 0;
        for (int w = 0; w < wid; w++) pre += wsum[w];
        lrow[t] = pre + xx - r4;
        lfill[t] = 0;
    }
    __syncthreads();

    /* scatter this quarter's edges into LDS CSR */
    for (int i = t; i < cnt; i += 1024) {
        unsigned int v = eb[i];
        int d = (v >> 10) & 1023;
        if ((d >> 8) == part) {
            int dl = d & 255;
            int pos = lrow[dl] + atomicAdd(&lfill[dl], 1);
            lcsr[pos] = (unsigned short)(v & 1023);
        }
    }
    __syncthreads();
    /* padding -> zero row */
    if (t < 256) {
        int st = lrow[t];
        for (int i = dq; i < r4; i++) lcsr[st + i] = 1024;
        int n = (g << 10) + part * 256 + t;
        disg[n] = rsqrtf((float)(dq + 1));
        rowinfo[n] = ((unsigned int)st << 16) | (unsigned int)dq;
    }
    __syncthreads();

    /* write quarter CSR to global (qlen multiple of 4) */
    int qlen = lrow[255] + ((uhist[part * 256 + 255] + 3) & ~3);
    {
        const ushort4* l4 = (const ushort4*)lcsr;
        ushort4* c4 = (ushort4*)(csr + (size_t)g * CSRG + part * CAPQ);
        for (int i = t; i < (qlen >> 2); i += 1024) c4[i] = l4[i];
    }

    /* stage hs = dis * (x @ W1^T) for ALL 1024 nodes, swizzled */
    {
        int n = (g << 10) + t;
        float inr[16];
        const float4* in4 = (const float4*)(x + (size_t)n * 16);
        #pragma unroll
        for (int k = 0; k < 4; k++) {
            float4 v = in4[k];
            inr[4*k] = v.x; inr[4*k+1] = v.y; inr[4*k+2] = v.z; inr[4*k+3] = v.w;
        }
        int sw = t & 7;
        #pragma unroll
        for (int o4 = 0; o4 < 8; o4++) {
            float r[4];
            #pragma unroll
            for (int j = 0; j < 4; j++) {
                int o = o4 * 4 + j;
                float s = 0.f;
                #pragma unroll
                for (int k = 0; k < 16; k++) s += inr[k] * W[o * 16 + k];
                r[j] = s * dis_own;
            }
            hsL4[t * 8 + (o4 ^ sw)] = make_float4(r[0], r[1], r[2], r[3]);
        }
    }
    __syncthreads();

    /* gather for this quarter's 256 nodes, 8 lanes/node, ushort4 quads */
    int q = t & 7, grp = t >> 3;
    #pragma unroll
    for (int pass = 0; pass < 2; pass++) {
        int lq = pass * 128 + grp;
        int ln = part * 256 + lq;
        int d = uhist[ln];
        float dn = rsqrtf((float)(d + 1));
        int st = lrow[lq];
        float4 acc = hsL4[ln * 8 + (q ^ (ln & 7))];
        const ushort4* c4 = (const ushort4*)(lcsr + st);
        int d4 = (d + 3) >> 2;
        for (int i = 0; i < d4; i++) {
            ushort4 ss = c4[i];
            float4 v0 = hsL4[ss.x * 8 + (q ^ (ss.x & 7))];
            float4 v1 = hsL4[ss.y * 8 + (q ^ (ss.y & 7))];
            float4 v2 = hsL4[ss.z * 8 + (q ^ (ss.z & 7))];
            float4 v3 = hsL4[ss.w * 8 + (q ^ (ss.w & 7))];
            acc.x += (v0.x + v1.x) + (v2.x + v3.x);
            acc.y += (v0.y + v1.y) + (v2.y + v3.y);
            acc.z += (v0.z + v1.z) + (v2.z + v3.z);
            acc.w += (v0.w + v1.w) + (v2.w + v3.w);
        }
        float4 bb = ((const float4*)bias)[q];
        float4 r;
        r.x = ftanh(dn * acc.x + bb.x);
        r.y = ftanh(dn * acc.y + bb.y);
        r.z = ftanh(dn * acc.z + bb.z);
        r.w = ftanh(dn * acc.w + bb.w);
        ((float4*)h1)[((size_t)(g << 10) + ln) * 8 + q] = r;
    }
}

/* ---- GCN layer 2 + Linear(Wl)+tanh + pooling (partial per block) ---- */
__global__ __launch_bounds__(1024, 1) void k_conv2(
        const float* __restrict__ h1, const float* __restrict__ W,
        const float* __restrict__ bias, const float* __restrict__ disg,
        const unsigned int* __restrict__ rowinfo, const unsigned short* __restrict__ csr,
        const float* __restrict__ Wl, const float* __restrict__ bl,
        float* __restrict__ pooled4) {
    __shared__ float hsL[1025 * 32];
    __shared__ float WlL[32 * 33];
    float4* hsL4 = (float4*)hsL;

    int t = threadIdx.x;
    int g = blockIdx.x >> 2, part = blockIdx.x & 3;

    if (t < 32 * 32) WlL[(t >> 5) * 33 + (t & 31)] = Wl[t];
    if (t < 32) hsL[1024 * 32 + t] = 0.f;

    /* stage hs2 = dis * (h1 @ W2^T) for ALL 1024 nodes */
    {
        int n = (g << 10) + t;
        float inr[32];
        const float4* in4 = (const float4*)(h1 + (size_t)n * 32);
        #pragma unroll
        for (int k = 0; k < 8; k++) {
            float4 v = in4[k];
            inr[4*k] = v.x; inr[4*k+1] = v.y; inr[4*k+2] = v.z; inr[4*k+3] = v.w;
        }
        float dn = disg[n];
        int sw = t & 7;
        #pragma unroll
        for (int o4 = 0; o4 < 8; o4++) {
            float r[4];
            #pragma unroll
            for (int j = 0; j < 4; j++) {
                int o = o4 * 4 + j;
                float s = 0.f;
                #pragma unroll
                for (int k = 0; k < 32; k++) s += inr[k] * W[o * 32 + k];
                r[j] = s * dn;
            }
            hsL4[t * 8 + (o4 ^ sw)] = make_float4(r[0], r[1], r[2], r[3]);
        }
    }
    __syncthreads();

    int q = t & 7, grp = t >> 3;
    float4 racc[2];
    #pragma unroll
    for (int pass = 0; pass < 2; pass++) {
        int lq = pass * 128 + grp;
        int ln = part * 256 + lq;
        int n = (g << 10) + ln;
        unsigned int ri = rowinfo[n];
        int st = ri >> 16;
        int d  = ri & 0xFFFF;
        float dn = rsqrtf((float)(d + 1));
        float4 acc = hsL4[ln * 8 + (q ^ (ln & 7))];
        const ushort4* c4 = (const ushort4*)(csr + (size_t)g * CSRG + part * CAPQ + st);
        int d4 = (d + 3) >> 2;
        for (int i = 0; i < d4; i++) {
            ushort4 ss = c4[i];
            float4 v0 = hsL4[ss.x * 8 + (q ^ (ss.x & 7))];
            float4 v1 = hsL4[ss.y * 8 + (q ^ (ss.y & 7))];
            float4 v2 = hsL4[ss.z * 8 + (q ^ (ss.z & 7))];
            float4 v3 = hsL4[ss.w * 8 + (q ^ (ss.w & 7))];
            acc.x += (v0.x + v1.x) + (v2.x + v3.x);
            acc.y += (v0.y + v1.y) + (v2.y + v3.y);
            acc.z += (v0.z + v1.z) + (v2.z + v3.z);
            acc.w += (v0.w + v1.w) + (v2.w + v3.w);
        }
        float4 bb = ((const float4*)bias)[q];
        float4 r;
        r.x = ftanh(dn * acc.x + bb.x);
        r.y = ftanh(dn * acc.y + bb.y);
        r.z = ftanh(dn * acc.z + bb.z);
        r.w = ftanh(dn * acc.w + bb.w);
        racc[pass] = r;
    }

    /* h3 = tanh(h2 @ Wl^T + bl), pool this block's 256 nodes */
    __syncthreads();
    #pragma unroll
    for (int pass = 0; pass < 2; pass++) {
        int lnn = pass * 128 + grp;
        hsL4[lnn * 8 + (q ^ (lnn & 7))] = racc[pass];
    }
    __syncthreads();
    int o = t & 31, seg = t >> 5;
    float ps = 0.f;
    #pragma unroll
    for (int j = 0; j < 8; j++) {
        int nl = seg * 8 + j;
        int swn = nl & 7;
        float s = bl[o];
        #pragma unroll
        for (int k = 0; k < 32; k++) {
            float h2v = hsL[nl * 32 + ((((k >> 2) ^ swn) << 2) | (k & 3))];
            s += h2v * WlL[o * 33 + k];
        }
        ps += ftanh(s);
    }
    float* psum = hsL + 8192;
    psum[t] = ps;
    __syncthreads();
    if (t < 32) {
        float tot = 0.f;
        for (int s = 0; s < 32; s++) tot += psum[s * 32 + t];
        pooled4[blockIdx.x * 32 + t] = tot;
    }
}

/* whole MLP tail: 64 graphs x 32 lanes */
__global__ void k_final(const float* __restrict__ pooled4, const float* __restrict__ share,
                        const float* __restrict__ Wp,  const float* __restrict__ bp,
                        const float* __restrict__ Vw1, const float* __restrict__ Vb1,
                        const float* __restrict__ Vw2, const float* __restrict__ Vb2,
                        const float* __restrict__ Vw3, const float* __restrict__ Vb3,
                        const float* __restrict__ Cw1, const float* __restrict__ Cb1,
                        const float* __restrict__ Cw2, const float* __restrict__ Cb2,
                        float* __restrict__ out) {
    int id = blockIdx.x * 256 + threadIdx.x;  /* 0..2047 */
    int b = id >> 5;
    int j = id & 31;
    float p = pooled4[(b * 4 + 0) * 32 + j] + pooled4[(b * 4 + 1) * 32 + j]
            + pooled4[(b * 4 + 2) * 32 + j] + pooled4[(b * 4 + 3) * 32 + j];
    float h1v = bp[j];
    #pragma unroll
    for (int k = 0; k < 32; k++) h1v += Wp[j * 32 + k] * __shfl(p, k, 32);
    float s0 = share[b * 64 + j];
    float s1 = share[b * 64 + 32 + j];
    float t1 = Vb1[j];
    #pragma unroll
    for (int k = 0; k < 32; k++) {
        t1 += Vw1[j * 64 + k] * __shfl(s0, k, 32);
        t1 += Vw1[j * 64 + 32 + k] * __shfl(s1, k, 32);
    }
    t1 = tanhf(t1);
    float t2 = Vb2[j];
    #pragma unroll
    for (int k = 0; k < 32; k++) t2 += Vw2[j * 32 + k] * __shfl(t1, k, 32);
    t2 = tanhf(t2);
    float h2v = Vb3[j];
    #pragma unroll
    for (int k = 0; k < 32; k++) h2v += Vw3[j * 32 + k] * __shfl(t2, k, 32);
    float z = Cb1[j];
    #pragma unroll
    for (int k = 0; k < 32; k++) {
        z += Cw1[j * 64 + k] * __shfl(h1v, k, 32);
        z += Cw1[j * 64 + 32 + k] * __shfl(h2v, k, 32);
    }
    z = tanhf(z);
    float v = Cw2[j] * z;
    v += __shfl_down(v, 16, 32); v += __shfl_down(v, 8, 32);
    v += __shfl_down(v, 4, 32);  v += __shfl_down(v, 2, 32);
    v += __shfl_down(v, 1, 32);
    if (j == 0) out[b] = v + Cb2[0];
}

extern "C" void kernel_launch(void* const* d_in, const int* in_sizes, int n_in,
                              void* d_out, int out_size, void* d_ws, size_t ws_size,
                              hipStream_t stream) {
    const float* x     = (const float*)d_in[0];
    const int*   ei    = (const int*)d_in[1];
    const float* share = (const float*)d_in[3];
    const float* W1 = (const float*)d_in[4];  const float* b1 = (const float*)d_in[5];
    const float* W2 = (const float*)d_in[6];  const float* b2 = (const float*)d_in[7];
    const float* Wl = (const float*)d_in[8];  const float* bl = (const float*)d_in[9];
    const float* Wp = (const float*)d_in[10]; const float* bp = (const float*)d_in[11];
    const float* Vw1 = (const float*)d_in[12]; const float* Vb1 = (const float*)d_in[13];
    const float* Vw2 = (const float*)d_in[14]; const float* Vb2 = (const float*)d_in[15];
    const float* Vw3 = (const float*)d_in[16]; const float* Vb3 = (const float*)d_in[17];
    const float* Cw1 = (const float*)d_in[18]; const float* Cb1 = (const float*)d_in[19];
    const float* Cw2 = (const float*)d_in[20]; const float* Cb2 = (const float*)d_in[21];

    char* ws = (char*)d_ws;
    int*            gfill   = (int*)(ws + OFF_GFILL);
    float*          pooled4 = (float*)(ws + OFF_POOL4);
    unsigned int*   rowinfo = (unsigned int*)(ws + OFF_ROWI);
    float*          disg    = (float*)(ws + OFF_DIS);
    unsigned short* csr     = (unsigned short*)(ws + OFF_CSR);
    unsigned int*   ebuf    = (unsigned int*)(ws + OFF_EBUF);
    float*          h1      = (float*)(ws + OFF_H1);

    const int* srcp = ei;
    const int* dstp = ei + NEDGES;

    hipMemsetAsync(gfill, 0, 256, stream);

    k_bucket<<<256, 256, 0, stream>>>(srcp, dstp, gfill, ebuf);
    k_build_conv1<<<256, 1024, 0, stream>>>(x, W1, b1, ebuf, gfill,
                                            disg, rowinfo, csr, h1);
    k_conv2<<<256, 1024, 0, stream>>>(h1, W2, b2, disg, rowinfo, csr,
                                      Wl, bl, pooled4);
    k_final<<<8, 256, 0, stream>>>(pooled4, share, Wp, bp, Vw1, Vb1, Vw2, Vb2,
                                   Vw3, Vb3, Cw1, Cb1, Cw2, Cb2, (float*)d_out);
}

// Round 5
// 186.749 us; speedup vs baseline: 2.3390x; 1.0254x over previous
//
#include <hip/hip_runtime.h>
#include <math.h>

#define NNODES 65536
#define NEDGES 2097152
#define PGRAPH 1024
#define NGRAPH 64
#define CAPE_E 34560   /* per-graph edge cap: mean 32768, sigma~180 -> +10 sigma  */
#define CAPQ   9728    /* per-quarter CSR cap: mean 8192 + align-pad<=768 + 8.5σ */
#define CSRG   (4 * CAPQ)

/* ws layout (bytes) */
#define OFF_GFILL 0u          /* int[64]                            */
#define OFF_POOL4 256u        /* float[256*32] partial pools        */
#define OFF_ROWI  33024u      /* uint[65536]  (start<<16)|deg       */
#define OFF_DIS   295168u     /* float[65536]                       */
#define OFF_CSR   557312u     /* ushort[64*CSRG] = 4980736 B        */
#define OFF_EBUF  5538048u    /* uint[64*CAPE_E] = 8847360 B        */
#define OFF_H1    14385408u   /* bf16[65536*32] = 4194304 B         */

__device__ __forceinline__ float ftanh(float x) {
    float e = __expf(2.f * x);
    return 1.f - 2.f * __builtin_amdgcn_rcpf(e + 1.f);
}

__device__ __forceinline__ unsigned short pack_bf16(float f) {
    unsigned int b = __float_as_uint(f);
    b += 0x7FFFu + ((b >> 16) & 1u);          /* RNE */
    return (unsigned short)(b >> 16);
}
__device__ __forceinline__ float unpack_bf16_lo(unsigned int u) {
    return __uint_as_float(u << 16);
}
__device__ __forceinline__ float unpack_bf16_hi(unsigned int u) {
    return __uint_as_float(u & 0xFFFF0000u);
}

/* ---- bucket edges by graph id (block-local counting sort, contiguous writes) ---- */
__global__ void k_bucket(const int* __restrict__ src, const int* __restrict__ dst,
                         int* __restrict__ gfill, unsigned int* __restrict__ ebuf) {
    __shared__ unsigned int sorted[8192];
    __shared__ int hist[64], lexcl[64], gbase[64], lfill[64];
    int t = threadIdx.x;
    if (t < 64) { hist[t] = 0; lfill[t] = 0; }
    __syncthreads();

    const int4* src4 = (const int4*)(src + blockIdx.x * 8192);
    const int4* dst4 = (const int4*)(dst + blockIdx.x * 8192);
    unsigned int pk[32];
    #pragma unroll
    for (int k = 0; k < 8; k++) {
        int4 s4 = src4[k * 256 + t];
        int4 d4 = dst4[k * 256 + t];
        int ss[4] = { s4.x, s4.y, s4.z, s4.w };
        int dd[4] = { d4.x, d4.y, d4.z, d4.w };
        #pragma unroll
        for (int j = 0; j < 4; j++) {
            int g = ss[j] >> 10;
            pk[k * 4 + j] = (unsigned int)((ss[j] & 1023) | ((dd[j] & 1023) << 10) | (g << 20));
            atomicAdd(&hist[g], 1);
        }
    }
    __syncthreads();
    if (t < 64) {
        int h = hist[t];
        int x = h;
        #pragma unroll
        for (int off = 1; off < 64; off <<= 1) {
            int y = __shfl_up(x, off, 64);
            if (t >= off) x += y;
        }
        lexcl[t] = x - h;
        gbase[t] = atomicAdd(&gfill[t], h);
    }
    __syncthreads();
    #pragma unroll
    for (int k = 0; k < 32; k++) {
        int g = pk[k] >> 20;
        int pos = lexcl[g] + atomicAdd(&lfill[g], 1);
        sorted[pos] = pk[k];
    }
    __syncthreads();
    for (int i = t; i < 8192; i += 256) {
        unsigned int p = sorted[i];
        int g = p >> 20;
        ebuf[(size_t)g * CAPE_E + gbase[g] + (i - lexcl[g])] = p;
    }
}

/* ---- fused: per-quarter CSR build (LDS) + GCN layer 1 (LDS-resident gather) ----
   XCD co-location: g = blockIdx&63, part = blockIdx>>6 -> the 4 blocks of a
   graph share one XCD's L2 (ebuf/h1 fetched once per XCD). */
__global__ __launch_bounds__(1024, 1) void k_build_conv1(
        const float* __restrict__ x, const float* __restrict__ W,
        const float* __restrict__ bias,
        const unsigned int* __restrict__ ebuf, const int* __restrict__ gfill,
        float* __restrict__ disg, unsigned int* __restrict__ rowinfo,
        unsigned short* __restrict__ csr, unsigned short* __restrict__ h1) {
    __shared__ float hsL[1025 * 32];          /* 131200 B, row 1024 = zeros */
    __shared__ unsigned short lcsr[CAPQ];     /* 19456 B */
    __shared__ int uhist[1024];
    __shared__ int lrow[256], lfill[256];
    __shared__ int wsum[4];
    float4* hsL4 = (float4*)hsL;

    int t = threadIdx.x;
    int g = blockIdx.x & 63, part = blockIdx.x >> 6;
    int cnt = gfill[g];
    const unsigned int* eb = ebuf + (size_t)g * CAPE_E;

    /* preload x row early so its latency overlaps the edge scans */
    float inr[16];
    {
        const float4* in4 = (const float4*)(x + ((size_t)(g << 10) + t) * 16);
        #pragma unroll
        for (int k = 0; k < 4; k++) {
            float4 v = in4[k];
            inr[4*k] = v.x; inr[4*k+1] = v.y; inr[4*k+2] = v.z; inr[4*k+3] = v.w;
        }
    }

    uhist[t] = 0;
    if (t < 32) hsL[1024 * 32 + t] = 0.f;     /* zero row */
    __syncthreads();
    for (int i = t; i < cnt; i += 1024) atomicAdd(&uhist[(eb[i] >> 10) & 1023], 1);
    __syncthreads();

    int dv_own = uhist[t];
    float dis_own = rsqrtf((float)(dv_own + 1));

    /* 256-wide exclusive scan of 4-aligned quarter degrees */
    int dq = 0, r4 = 0;
    if (t < 256) { dq = uhist[part * 256 + t]; r4 = (dq + 3) & ~3; }
    int lane = t & 63, wid = t >> 6;
    int xx = r4;
    #pragma unroll
    for (int off = 1; off < 64; off <<= 1) {
        int y = __shfl_up(xx, off, 64);
        if (lane >= off) xx += y;
    }
    if (t < 256 && lane == 63) wsum[wid] = xx;
    __syncthreads();
    if (t < 256) {
        int pre = 0;
        for (int w = 0; w < wid; w++) pre += wsum[w];
        lrow[t] = pre + xx - r4;
        lfill[t] = 0;
    }
    __syncthreads();

    /* scatter this quarter's edges into LDS CSR (eb is local-L2-warm now) */
    for (int i = t; i < cnt; i += 1024) {
        unsigned int v = eb[i];
        int d = (v >> 10) & 1023;
        if ((d >> 8) == part) {
            int dl = d & 255;
            int pos = lrow[dl] + atomicAdd(&lfill[dl], 1);
            lcsr[pos] = (unsigned short)(v & 1023);
        }
    }
    __syncthreads();
    /* padding -> zero row */
    if (t < 256) {
        int st = lrow[t];
        for (int i = dq; i < r4; i++) lcsr[st + i] = 1024;
        int n = (g << 10) + part * 256 + t;
        disg[n] = rsqrtf((float)(dq + 1));
        rowinfo[n] = ((unsigned int)st << 16) | (unsigned int)dq;
    }
    __syncthreads();

    /* write quarter CSR to global (qlen multiple of 4) */
    int qlen = lrow[255] + ((uhist[part * 256 + 255] + 3) & ~3);
    {
        const ushort4* l4 = (const ushort4*)lcsr;
        ushort4* c4 = (ushort4*)(csr + (size_t)g * CSRG + part * CAPQ);
        for (int i = t; i < (qlen >> 2); i += 1024) c4[i] = l4[i];
    }

    /* stage hs = dis * (x @ W1^T) for ALL 1024 nodes, swizzled */
    {
        int sw = t & 7;
        #pragma unroll
        for (int o4 = 0; o4 < 8; o4++) {
            float r[4];
            #pragma unroll
            for (int j = 0; j < 4; j++) {
                int o = o4 * 4 + j;
                float s = 0.f;
                #pragma unroll
                for (int k = 0; k < 16; k++) s += inr[k] * W[o * 16 + k];
                r[j] = s * dis_own;
            }
            hsL4[t * 8 + (o4 ^ sw)] = make_float4(r[0], r[1], r[2], r[3]);
        }
    }
    __syncthreads();

    /* gather for this quarter's 256 nodes, 8 lanes/node, ushort4 quads */
    int q = t & 7, grp = t >> 3;
    #pragma unroll
    for (int pass = 0; pass < 2; pass++) {
        int lq = pass * 128 + grp;
        int ln = part * 256 + lq;
        int d = uhist[ln];
        float dn = rsqrtf((float)(d + 1));
        int st = lrow[lq];
        float4 acc = hsL4[ln * 8 + (q ^ (ln & 7))];
        const ushort4* c4 = (const ushort4*)(lcsr + st);
        int d4 = (d + 3) >> 2;
        for (int i = 0; i < d4; i++) {
            ushort4 ss = c4[i];
            float4 v0 = hsL4[ss.x * 8 + (q ^ (ss.x & 7))];
            float4 v1 = hsL4[ss.y * 8 + (q ^ (ss.y & 7))];
            float4 v2 = hsL4[ss.z * 8 + (q ^ (ss.z & 7))];
            float4 v3 = hsL4[ss.w * 8 + (q ^ (ss.w & 7))];
            acc.x += (v0.x + v1.x) + (v2.x + v3.x);
            acc.y += (v0.y + v1.y) + (v2.y + v3.y);
            acc.z += (v0.z + v1.z) + (v2.z + v3.z);
            acc.w += (v0.w + v1.w) + (v2.w + v3.w);
        }
        float4 bb = ((const float4*)bias)[q];
        ushort4 r;
        r.x = pack_bf16(ftanh(dn * acc.x + bb.x));
        r.y = pack_bf16(ftanh(dn * acc.y + bb.y));
        r.z = pack_bf16(ftanh(dn * acc.z + bb.z));
        r.w = pack_bf16(ftanh(dn * acc.w + bb.w));
        ((ushort4*)h1)[((size_t)(g << 10) + ln) * 8 + q] = r;
    }
}

/* ---- GCN layer 2 + Linear(Wl)+tanh + pooling (partial per block) ---- */
__global__ __launch_bounds__(1024, 1) void k_conv2(
        const unsigned short* __restrict__ h1, const float* __restrict__ W,
        const float* __restrict__ bias, const float* __restrict__ disg,
        const unsigned int* __restrict__ rowinfo, const unsigned short* __restrict__ csr,
        const float* __restrict__ Wl, const float* __restrict__ bl,
        float* __restrict__ pooled4) {
    __shared__ float hsL[1025 * 32];
    __shared__ float WlL[32 * 33];
    float4* hsL4 = (float4*)hsL;

    int t = threadIdx.x;
    int g = blockIdx.x & 63, part = blockIdx.x >> 6;

    /* preload h1 row (bf16 packed) early */
    float inr[32];
    {
        const uint4* in4 = (const uint4*)(h1 + ((size_t)(g << 10) + t) * 32);
        #pragma unroll
        for (int k = 0; k < 4; k++) {
            uint4 v = in4[k];
            unsigned int uu[4] = { v.x, v.y, v.z, v.w };
            #pragma unroll
            for (int j = 0; j < 4; j++) {
                inr[8*k + 2*j]     = unpack_bf16_lo(uu[j]);
                inr[8*k + 2*j + 1] = unpack_bf16_hi(uu[j]);
            }
        }
    }
    float dn_own = disg[(g << 10) + t];

    if (t < 32 * 32) WlL[(t >> 5) * 33 + (t & 31)] = Wl[t];
    if (t < 32) hsL[1024 * 32 + t] = 0.f;
    __syncthreads();

    /* stage hs2 = dis * (h1 @ W2^T) for ALL 1024 nodes */
    {
        int sw = t & 7;
        #pragma unroll
        for (int o4 = 0; o4 < 8; o4++) {
            float r[4];
            #pragma unroll
            for (int j = 0; j < 4; j++) {
                int o = o4 * 4 + j;
                float s = 0.f;
                #pragma unroll
                for (int k = 0; k < 32; k++) s += inr[k] * W[o * 32 + k];
                r[j] = s * dn_own;
            }
            hsL4[t * 8 + (o4 ^ sw)] = make_float4(r[0], r[1], r[2], r[3]);
        }
    }
    __syncthreads();

    int q = t & 7, grp = t >> 3;
    float4 racc[2];
    #pragma unroll
    for (int pass = 0; pass < 2; pass++) {
        int lq = pass * 128 + grp;
        int ln = part * 256 + lq;
        int n = (g << 10) + ln;
        unsigned int ri = rowinfo[n];
        int st = ri >> 16;
        int d  = ri & 0xFFFF;
        float dn = rsqrtf((float)(d + 1));
        float4 acc = hsL4[ln * 8 + (q ^ (ln & 7))];
        const ushort4* c4 = (const ushort4*)(csr + (size_t)g * CSRG + part * CAPQ + st);
        int d4 = (d + 3) >> 2;
        for (int i = 0; i < d4; i++) {
            ushort4 ss = c4[i];
            float4 v0 = hsL4[ss.x * 8 + (q ^ (ss.x & 7))];
            float4 v1 = hsL4[ss.y * 8 + (q ^ (ss.y & 7))];
            float4 v2 = hsL4[ss.z * 8 + (q ^ (ss.z & 7))];
            float4 v3 = hsL4[ss.w * 8 + (q ^ (ss.w & 7))];
            acc.x += (v0.x + v1.x) + (v2.x + v3.x);
            acc.y += (v0.y + v1.y) + (v2.y + v3.y);
            acc.z += (v0.z + v1.z) + (v2.z + v3.z);
            acc.w += (v0.w + v1.w) + (v2.w + v3.w);
        }
        float4 bb = ((const float4*)bias)[q];
        float4 r;
        r.x = ftanh(dn * acc.x + bb.x);
        r.y = ftanh(dn * acc.y + bb.y);
        r.z = ftanh(dn * acc.z + bb.z);
        r.w = ftanh(dn * acc.w + bb.w);
        racc[pass] = r;
    }

    /* h3 = tanh(h2 @ Wl^T + bl), pool this block's 256 nodes */
    __syncthreads();
    #pragma unroll
    for (int pass = 0; pass < 2; pass++) {
        int lnn = pass * 128 + grp;
        hsL4[lnn * 8 + (q ^ (lnn & 7))] = racc[pass];
    }
    __syncthreads();
    int o = t & 31, seg = t >> 5;
    float ps = 0.f;
    #pragma unroll
    for (int j = 0; j < 8; j++) {
        int nl = seg * 8 + j;
        int swn = nl & 7;
        float s = bl[o];
        #pragma unroll
        for (int k = 0; k < 32; k++) {
            float h2v = hsL[nl * 32 + ((((k >> 2) ^ swn) << 2) | (k & 3))];
            s += h2v * WlL[o * 33 + k];
        }
        ps += ftanh(s);
    }
    float* psum = hsL + 8192;
    psum[t] = ps;
    __syncthreads();
    if (t < 32) {
        float tot = 0.f;
        for (int s = 0; s < 32; s++) tot += psum[s * 32 + t];
        pooled4[(g * 4 + part) * 32 + t] = tot;
    }
}

/* whole MLP tail: 64 graphs x 32 lanes */
__global__ void k_final(const float* __restrict__ pooled4, const float* __restrict__ share,
                        const float* __restrict__ Wp,  const float* __restrict__ bp,
                        const float* __restrict__ Vw1, const float* __restrict__ Vb1,
                        const float* __restrict__ Vw2, const float* __restrict__ Vb2,
                        const float* __restrict__ Vw3, const float* __restrict__ Vb3,
                        const float* __restrict__ Cw1, const float* __restrict__ Cb1,
                        const float* __restrict__ Cw2, const float* __restrict__ Cb2,
                        float* __restrict__ out) {
    int id = blockIdx.x * 256 + threadIdx.x;  /* 0..2047 */
    int b = id >> 5;
    int j = id & 31;
    float p = pooled4[(b * 4 + 0) * 32 + j] + pooled4[(b * 4 + 1) * 32 + j]
            + pooled4[(b * 4 + 2) * 32 + j] + pooled4[(b * 4 + 3) * 32 + j];
    float h1v = bp[j];
    #pragma unroll
    for (int k = 0; k < 32; k++) h1v += Wp[j * 32 + k] * __shfl(p, k, 32);
    float s0 = share[b * 64 + j];
    float s1 = share[b * 64 + 32 + j];
    float t1 = Vb1[j];
    #pragma unroll
    for (int k = 0; k < 32; k++) {
        t1 += Vw1[j * 64 + k] * __shfl(s0, k, 32);
        t1 += Vw1[j * 64 + 32 + k] * __shfl(s1, k, 32);
    }
    t1 = tanhf(t1);
    float t2 = Vb2[j];
    #pragma unroll
    for (int k = 0; k < 32; k++) t2 += Vw2[j * 32 + k] * __shfl(t1, k, 32);
    t2 = tanhf(t2);
    float h2v = Vb3[j];
    #pragma unroll
    for (int k = 0; k < 32; k++) h2v += Vw3[j * 32 + k] * __shfl(t2, k, 32);
    float z = Cb1[j];
    #pragma unroll
    for (int k = 0; k < 32; k++) {
        z += Cw1[j * 64 + k] * __shfl(h1v, k, 32);
        z += Cw1[j * 64 + 32 + k] * __shfl(h2v, k, 32);
    }
    z = tanhf(z);
    float v = Cw2[j] * z;
    v += __shfl_down(v, 16, 32); v += __shfl_down(v, 8, 32);
    v += __shfl_down(v, 4, 32);  v += __shfl_down(v, 2, 32);
    v += __shfl_down(v, 1, 32);
    if (j == 0) out[b] = v + Cb2[0];
}

extern "C" void kernel_launch(void* const* d_in, const int* in_sizes, int n_in,
                              void* d_out, int out_size, void* d_ws, size_t ws_size,
                              hipStream_t stream) {
    const float* x     = (const float*)d_in[0];
    const int*   ei    = (const int*)d_in[1];
    const float* share = (const float*)d_in[3];
    const float* W1 = (const float*)d_in[4];  const float* b1 = (const float*)d_in[5];
    const float* W2 = (const float*)d_in[6];  const float* b2 = (const float*)d_in[7];
    const float* Wl = (const float*)d_in[8];  const float* bl = (const float*)d_in[9];
    const float* Wp = (const float*)d_in[10]; const float* bp = (const float*)d_in[11];
    const float* Vw1 = (const float*)d_in[12]; const float* Vb1 = (const float*)d_in[13];
    const float* Vw2 = (const float*)d_in[14]; const float* Vb2 = (const float*)d_in[15];
    const float* Vw3 = (const float*)d_in[16]; const float* Vb3 = (const float*)d_in[17];
    const float* Cw1 = (const float*)d_in[18]; const float* Cb1 = (const float*)d_in[19];
    const float* Cw2 = (const float*)d_in[20]; const float* Cb2 = (const float*)d_in[21];

    char* ws = (char*)d_ws;
    int*            gfill   = (int*)(ws + OFF_GFILL);
    float*          pooled4 = (float*)(ws + OFF_POOL4);
    unsigned int*   rowinfo = (unsigned int*)(ws + OFF_ROWI);
    float*          disg    = (float*)(ws + OFF_DIS);
    unsigned short* csr     = (unsigned short*)(ws + OFF_CSR);
    unsigned int*   ebuf    = (unsigned int*)(ws + OFF_EBUF);
    unsigned short* h1      = (unsigned short*)(ws + OFF_H1);

    const int* srcp = ei;
    const int* dstp = ei + NEDGES;

    hipMemsetAsync(gfill, 0, 256, stream);

    k_bucket<<<256, 256, 0, stream>>>(srcp, dstp, gfill, ebuf);
    k_build_conv1<<<256, 1024, 0, stream>>>(x, W1, b1, ebuf, gfill,
                                            disg, rowinfo, csr, h1);
    k_conv2<<<256, 1024, 0, stream>>>(h1, W2, b2, disg, rowinfo, csr,
                                      Wl, bl, pooled4);
    k_final<<<8, 256, 0, stream>>>(pooled4, share, Wp, bp, Vw1, Vb1, Vw2, Vb2,
                                   Vw3, Vb3, Cw1, Cb1, Cw2, Cb2, (float*)d_out);
}